// Round 6
// baseline (905.139 us; speedup 1.0000x reference)
//
#include <hip/hip_runtime.h>

// DeepSeek-V2 expert MLP, fp8-block-dequant weights. T=8192, H=5120, F=1536.
// Pipeline (3 dispatches):
//   1) prep: x f32->bf16; wg,wu dequant->bf16 INTERLEAVED into wq[3072][5120];
//      wd dequant->bf16 wdq[5120][1536].  (unchanged, verified)
//   2) gemm_p<FUSE_SILU>: h = silu/up-pair epilogue of xb @ wq^T.
//   3) gemm_p<plain>: out = h @ wdq^T, f32.
// GEMM round-6: R5 skeleton (tile 128x256, 256 thr = 4 waves, per-wave
// 128x64, 32x32x16 MFMA core, ring-3 LDS 72 KB => 2 blocks/CU, 2 phases/
// kslice, counted VMBAR(6)) with FRAGMENT-MAJOR LDS layout replacing the
// XOR swizzle (which measured 2.36e7 conflicts in R5):
//   slab = 32 rows x 32 k = 2048 B; chunk c_local = (kk<<6)|(kh<<5)|row5;
//   fragment read = slab_base + kk*1024 + lane*16  -- lane-LINEAR, the
//   canonical zero-conflict pattern (same as glds writes). No XOR anywhere;
//   the permutation lives in the per-lane GLOBAL source address (m173).
// C/D layout = m74/m101-verified col=lane&31, row=(reg&3)+8*(reg>>2)+
// 4*(lane>>5) (R5 passed refcheck with it).
// Kept verified: setprio [T5], bijective XCD chunk swizzle [T1]
// (grids 768/1280, %8==0), counted-vmcnt cadence [T4].

typedef __bf16 bf16x8 __attribute__((ext_vector_type(8)));
typedef float  f32x4  __attribute__((ext_vector_type(4)));
typedef float  f32x16 __attribute__((ext_vector_type(16)));

__device__ __forceinline__ void glds16(const __bf16* g, __bf16* l) {
  __builtin_amdgcn_global_load_lds(
      (const __attribute__((address_space(1))) void*)g,
      (__attribute__((address_space(3))) void*)l, 16, 0, 0);
}

// Fragment-major chunk map: linear 16B LDS chunk c holds global
// (row, k8) = ((c>>7)*32 + (c&31), ((c>>6)&1)*16 + ((c>>5)&1)*8).
__device__ __forceinline__ void chunk_rk(int c, int& row, int& k8) {
  row = ((c >> 7) << 5) | (c & 31);
  k8 = (((c >> 6) & 1) << 4) | (((c >> 5) & 1) << 3);
}

#define BAR()                               \
  do {                                      \
    __builtin_amdgcn_sched_barrier(0);      \
    asm volatile("s_barrier" ::: "memory"); \
    __builtin_amdgcn_sched_barrier(0);      \
  } while (0)

#define LGKM0()                                        \
  do {                                                 \
    asm volatile("s_waitcnt lgkmcnt(0)" ::: "memory"); \
    __builtin_amdgcn_sched_barrier(0);                 \
  } while (0)

#define VMBAR(n)                                                       \
  do {                                                                 \
    __builtin_amdgcn_sched_barrier(0);                                 \
    asm volatile("s_waitcnt vmcnt(" #n ")\n\ts_barrier" ::: "memory"); \
    __builtin_amdgcn_sched_barrier(0);                                 \
  } while (0)

// ---- fused prep: xcast + 3 dequants in one launch (unchanged) -------------
__device__ __forceinline__ void cast8(const float* __restrict__ in,
                                      __bf16* __restrict__ out, size_t idx) {
  f32x4 a = *(const f32x4*)(in + idx);
  f32x4 b = *(const f32x4*)(in + idx + 4);
  bf16x8 o;
#pragma unroll
  for (int i = 0; i < 4; ++i) { o[i] = (__bf16)a[i]; o[i + 4] = (__bf16)b[i]; }
  *(bf16x8*)(out + idx) = o;
}

__device__ __forceinline__ void dq_ilv(const float* __restrict__ w,
                                       const float* __restrict__ s,
                                       __bf16* __restrict__ wq, int r, int tid,
                                       int which) {
  unsigned idx = ((unsigned)r * 256u + (unsigned)tid) * 8u;
  unsigned f = idx / 5120u;
  unsigned h = idx - f * 5120u;
  float sc = s[(f >> 7) * 40 + (h >> 7)];
  f32x4 a = *(const f32x4*)(w + idx);
  f32x4 b = *(const f32x4*)(w + idx + 4);
  bf16x8 o;
#pragma unroll
  for (int i = 0; i < 4; ++i) {
    o[i] = (__bf16)(a[i] * sc);
    o[i + 4] = (__bf16)(b[i] * sc);
  }
  *(bf16x8*)(wq + (size_t)(2 * f + which) * 5120 + h) = o;
}

__device__ __forceinline__ void dq_wd(const float* __restrict__ w,
                                      const float* __restrict__ s,
                                      __bf16* __restrict__ o8, int r, int tid) {
  unsigned idx = ((unsigned)r * 256u + (unsigned)tid) * 8u;
  unsigned f = idx / 1536u;
  unsigned h = idx - f * 1536u;
  float sc = s[(f >> 7) * 12 + (h >> 7)];
  f32x4 a = *(const f32x4*)(w + idx);
  f32x4 b = *(const f32x4*)(w + idx + 4);
  bf16x8 o;
#pragma unroll
  for (int i = 0; i < 4; ++i) {
    o[i] = (__bf16)(a[i] * sc);
    o[i + 4] = (__bf16)(b[i] * sc);
  }
  *(bf16x8*)(o8 + idx) = o;
}

__global__ void prep(const float* __restrict__ x, const float* __restrict__ wg,
                     const float* __restrict__ sg, const float* __restrict__ wu,
                     const float* __restrict__ su, const float* __restrict__ wd,
                     const float* __restrict__ sd, __bf16* __restrict__ xb,
                     __bf16* __restrict__ wq, __bf16* __restrict__ wdq) {
  int bid = blockIdx.x;
  int tid = threadIdx.x;
  if (bid < 20480) {
    cast8(x, xb, ((size_t)bid * 256 + tid) * 8);
  } else if (bid < 24320) {
    dq_ilv(wg, sg, wq, bid - 20480, tid, 0);
  } else if (bid < 28160) {
    dq_ilv(wu, su, wq, bid - 24320, tid, 1);
  } else {
    dq_wd(wd, sd, wdq, bid - 28160, tid);
  }
}

// ---- pipelined GEMM: C = A @ B^T ------------------------------------------
// A:[M,K] bf16, B:[N,K] bf16. Tile 128(M) x 256(N), 4 waves, kslice ring-3.
// Wave w owns N-stripe w*64 (2 x 32-col frags), full 128 M rows (4 x 32-row
// frags). acc[4][2] of f32x16. 16 x 32x32x16 MFMA per kslice.
template <bool FUSE_SILU, typename OutT>
__global__ __launch_bounds__(256, 2) void gemm_p(
    const __bf16* __restrict__ A, const __bf16* __restrict__ B,
    OutT* __restrict__ C, int M, int N, int K, int ldc, int nbx) {
  __shared__ __bf16 lds[3 * 12288];  // slot = A 4096 + B 8192 bf16 = 24 KB
  const int tid = threadIdx.x;
  const int lane = tid & 63;
  const int wave = tid >> 6;   // 0..3 = N-wave (each wave: 128 x 64 output)

  // bijective XCD-chunked swizzle (gridDim.x % 8 == 0 by construction)
  const int nwg = gridDim.x;
  const int lb = (blockIdx.x & 7) * (nwg >> 3) + (blockIdx.x >> 3);
  const int bx = lb % nbx;
  const int by = lb / nbx;
  const int m0 = by * 128, n0 = bx * 256;

  // staging: per kslice each thread: A chunks {tid, tid+256} (8 KB total),
  // B chunks {tid, tid+256, tid+512, tid+768} (16 KB total); fragment-major
  // global source permutation, linear LDS destination.
  int rr[4], kk[4];
  chunk_rk(tid, rr[0], kk[0]);
  chunk_rk(tid + 256, rr[1], kk[1]);
  chunk_rk(tid + 512, rr[2], kk[2]);
  chunk_rk(tid + 768, rr[3], kk[3]);
  const unsigned o0 = (unsigned)rr[0] * K + (unsigned)kk[0];
  const unsigned o1 = (unsigned)rr[1] * K + (unsigned)kk[1];
  const unsigned o2 = (unsigned)rr[2] * K + (unsigned)kk[2];
  const unsigned o3 = (unsigned)rr[3] * K + (unsigned)kk[3];
  const int d0 = tid << 3, d1 = (tid + 256) << 3;
  const int d2 = (tid + 512) << 3, d3 = (tid + 768) << 3;
  const __bf16* Ab = A + (size_t)m0 * K;
  const __bf16* Bb = B + (size_t)n0 * K;

  f32x16 acc[4][2] = {};
  bf16x8 af[4], bg[2];

  auto STAGE_P0 = [&](int t, int s) {  // A (2 loads) + B lower half (2)
    __bf16* sb = lds + s * 12288;
    const unsigned ko = (unsigned)t << 5;
    glds16(Ab + (o0 + ko), sb + d0);
    glds16(Ab + (o1 + ko), sb + d1);
    glds16(Bb + (o0 + ko), sb + 4096 + d0);
    glds16(Bb + (o1 + ko), sb + 4096 + d1);
  };
  auto STAGE_P1 = [&](int t, int s) {  // B upper half (2 loads)
    __bf16* sb = lds + s * 12288;
    const unsigned ko = (unsigned)t << 5;
    glds16(Bb + (o2 + ko), sb + 4096 + d2);
    glds16(Bb + (o3 + ko), sb + 4096 + d3);
  };
  // fragment reads: lane-linear within each 2048-B slab half (zero-conflict)
  auto RD = [&](const char* cb, int kko) {
#pragma unroll
    for (int i = 0; i < 4; ++i)
      af[i] = *(const bf16x8*)(cb + i * 2048 + kko + (lane << 4));
#pragma unroll
    for (int j = 0; j < 2; ++j)
      bg[j] = *(const bf16x8*)(cb + 8192 + ((wave * 2 + j) * 2048) + kko +
                               (lane << 4));
  };
  auto MFMA8 = [&] {
    __builtin_amdgcn_s_setprio(1);
#pragma unroll
    for (int j = 0; j < 2; ++j)
#pragma unroll
      for (int i = 0; i < 4; ++i)
        acc[i][j] = __builtin_amdgcn_mfma_f32_32x32x16_bf16(af[i], bg[j],
                                                            acc[i][j], 0, 0, 0);
    __builtin_amdgcn_s_setprio(0);
  };

  const int NT = K >> 5;  // 160 (gemm1) / 48 (gemm2)

  // prologue: stage kslices 0,1 (12 loads); wait oldest 6 (slice 0 ready)
  STAGE_P0(0, 0);
  STAGE_P1(0, 0);
  STAGE_P0(1, 1);
  STAGE_P1(1, 1);
  VMBAR(6);

  int cur = 0, stg = 2;
  for (int t = 0; t < NT - 2; ++t) {
    const char* cb = (const char*)lds + cur * 24576;
    RD(cb, 0);
    STAGE_P0(t + 2, stg);
    BAR();
    LGKM0();
    MFMA8();
    BAR();
    RD(cb, 1024);
    STAGE_P1(t + 2, stg);
    BAR();
    LGKM0();
    MFMA8();
    VMBAR(6);  // slice t+1 fully staged; slice t+2's 6 loads stay in flight
    cur = (cur == 2) ? 0 : cur + 1;
    stg = (stg == 2) ? 0 : stg + 1;
  }
  {  // t = NT-2: no staging; drain to 0 so slice NT-1 is readable
    const char* cb = (const char*)lds + cur * 24576;
    RD(cb, 0);
    BAR();
    LGKM0();
    MFMA8();
    BAR();
    RD(cb, 1024);
    BAR();
    LGKM0();
    MFMA8();
    VMBAR(0);
    cur = (cur == 2) ? 0 : cur + 1;
  }
  {  // t = NT-1: last slice
    const char* cb = (const char*)lds + cur * 24576;
    RD(cb, 0);
    LGKM0();
    MFMA8();
    RD(cb, 1024);
    LGKM0();
    MFMA8();
  }

  // C/D layout for 32x32 (m74/m101-verified):
  // col = lane&31, row = (reg&3) + 8*(reg>>2) + 4*(lane>>5).
  const int colx = n0 + (wave << 6) + (lane & 31);
  const int rbase = m0 + ((lane >> 5) << 2);
#pragma unroll
  for (int i = 0; i < 4; ++i)
#pragma unroll
    for (int j = 0; j < 2; ++j)
#pragma unroll
      for (int r = 0; r < 16; ++r) {
        const int row = rbase + i * 32 + (r & 3) + ((r >> 2) << 3);
        const int col = colx + j * 32;
        if constexpr (FUSE_SILU) {
          // lanes (2k,2k+1) hold cols (gate_f, up_f) of the same row.
          float v = acc[i][j][r];
          float p = __shfl_xor(v, 1, 64);
          float g = (lane & 1) ? p : v;
          float u = (lane & 1) ? v : p;
          float hv = (g / (1.0f + __expf(-g))) * u;
          if ((lane & 1) == 0)
            C[(size_t)row * ldc + (col >> 1)] = (OutT)hv;
        } else {
          C[(size_t)row * ldc + col] = (OutT)acc[i][j][r];
        }
      }
}

extern "C" void kernel_launch(void* const* d_in, const int* in_sizes, int n_in,
                              void* d_out, int out_size, void* d_ws,
                              size_t ws_size, hipStream_t stream) {
  const int Hd = 5120, Fd = 1536, Td = 8192;
  const float* x = (const float*)d_in[0];
  const float* wg = (const float*)d_in[1];
  const float* sg = (const float*)d_in[2];
  const float* wu = (const float*)d_in[3];
  const float* su = (const float*)d_in[4];
  const float* wd = (const float*)d_in[5];
  const float* sd = (const float*)d_in[6];
  float* out = (float*)d_out;

  // ws layout (bf16): xb [T*H] | wq [2F*H] | wdq [H*F] | h [T*F]  ~156 MB
  __bf16* ws = (__bf16*)d_ws;
  const size_t xsz = (size_t)Td * Hd;
  __bf16* xb = ws;
  __bf16* wq = xb + xsz;
  __bf16* wdq = wq + (size_t)2 * Fd * Hd;
  __bf16* hbuf = wdq + (size_t)Hd * Fd;

  prep<<<32000, 256, 0, stream>>>(x, wg, sg, wu, su, wd, sd, xb, wq, wdq);

  // gemm1: [8192 x 3072] = xb @ wq^T, silu-pair epilogue -> h [8192][1536]
  // grid = (8192/128) * (3072/256) = 64 * 12 = 768 (%8==0); 2 blk/CU
  gemm_p<true, __bf16><<<768, 256, 0, stream>>>(xb, wq, hbuf, Td, 2 * Fd, Hd,
                                                Fd, 12);

  // gemm2: [8192 x 5120] = h @ wdq^T -> out f32
  // grid = 64 * 20 = 1280 (%8==0); 2 blk/CU
  gemm_p<false, float><<<1280, 256, 0, stream>>>(hbuf, wdq, out, Td, Hd, Fd,
                                                 Hd, 20);
}

// Round 7
// 698.294 us; speedup vs baseline: 1.2962x; 1.2962x over previous
//
#include <hip/hip_runtime.h>

// DeepSeek-V2 expert MLP, fp8-block-dequant weights. T=8192, H=5120, F=1536.
// Round-7 "flatmm": B operand never touches LDS.
//   1) prep: x f32->bf16 (unchanged); wg,wu dequant -> wq in FRAGMENT-MAJOR
//      order (gate/up interleaved cols: nc=2f+which); wd dequant -> wdq
//      fragment-major. Chunk g (16B) holds W[nc][k..k+7] with
//      nc=(bx<<8)|(fr<<4)|(g&15), k=(t<<5)|(((g>>4)&3)<<3),
//      g=((bx*NT+t)*16+fr)*64+lane. Prep writes coalesced (chunk-order);
//      scattered 32B reads on weights (~2x amp, acceptable).
//   2/3) gemm_p: tile 128x256, 256 thr = 4 waves (per-wave 128x64, acc[8][4],
//      16x16x32 core -- R4-verified epilogue/layouts). A staged via glds into
//      ring-4 LDS (32 KB) with R4's verified XOR swizzle (0 conflicts);
//      B loaded direct global->VGPR via asm global_load_dwordx4 from the
//      fragment-major layout (1 coalesced 1KB load per wave per frag),
//      double-banked by kslice parity, prefetch distance 2.
//      ONE barrier per kslice: VMBAR(6) (A(t)2+B(t)4 drained, t+1's 6 in
//      flight) [T4]. setprio [T5], XCD swizzle [T1] kept. Uniform clamped
//      tail (redundant loads, never read).

typedef __bf16 bf16x8 __attribute__((ext_vector_type(8)));
typedef float  f32x4  __attribute__((ext_vector_type(4)));
typedef unsigned int u32x4 __attribute__((ext_vector_type(4)));

__device__ __forceinline__ void glds16(const __bf16* g, __bf16* l) {
  __builtin_amdgcn_global_load_lds(
      (const __attribute__((address_space(1))) void*)g,
      (__attribute__((address_space(3))) void*)l, 16, 0, 0);
}

// A-side inverse swizzle (R4-verified pair with laneoff below; 0 conflicts).
__device__ __forceinline__ void chunk_rk(int c, int& row, int& k) {
  int s = c >> 6;
  int w = (c & 63) << 4;
  int wl = w ^ (((w >> 9) & 1) << 5) ^ (((w >> 7) & 1) << 4);
  row = (s << 4) + (wl >> 6);
  k = (wl & 63) >> 1;
}

#define LGKM0()                                        \
  do {                                                 \
    asm volatile("s_waitcnt lgkmcnt(0)" ::: "memory"); \
    __builtin_amdgcn_sched_barrier(0);                 \
  } while (0)

#define VMBAR(n)                                                       \
  do {                                                                 \
    __builtin_amdgcn_sched_barrier(0);                                 \
    asm volatile("s_waitcnt vmcnt(" #n ")\n\ts_barrier" ::: "memory"); \
    __builtin_amdgcn_sched_barrier(0);                                 \
  } while (0)

// ---- prep: xcast + fragment-major dequants --------------------------------
__device__ __forceinline__ void cast8(const float* __restrict__ in,
                                      __bf16* __restrict__ out, size_t idx) {
  f32x4 a = *(const f32x4*)(in + idx);
  f32x4 b = *(const f32x4*)(in + idx + 4);
  bf16x8 o;
#pragma unroll
  for (int i = 0; i < 4; ++i) { o[i] = (__bf16)a[i]; o[i + 4] = (__bf16)b[i]; }
  *(bf16x8*)(out + idx) = o;
}

__global__ void prep(const float* __restrict__ x, const float* __restrict__ wg,
                     const float* __restrict__ sg, const float* __restrict__ wu,
                     const float* __restrict__ su, const float* __restrict__ wd,
                     const float* __restrict__ sd, __bf16* __restrict__ xb,
                     __bf16* __restrict__ wq, __bf16* __restrict__ wdq) {
  int bid = blockIdx.x;
  int tid = threadIdx.x;
  if (bid < 20480) {
    cast8(x, xb, ((size_t)bid * 256 + tid) * 8);
  } else if (bid < 28160) {
    // wq fragment-major (NT=160, 12 col-blocks of 256; nc = 2f+which).
    unsigned g = (unsigned)(bid - 20480) * 256u + (unsigned)tid;
    unsigned lane = g & 63u, c = lane & 15u, q = lane >> 4;
    unsigned fr = (g >> 6) & 15u;
    unsigned u = g >> 10;            // bx*160 + t  (< 1920)
    unsigned bx = u / 160u;
    unsigned t = u - bx * 160u;
    unsigned nc = (bx << 8) | (fr << 4) | c;
    unsigned k = (t << 5) | (q << 3);
    unsigned f = nc >> 1;
    const float* wsrc = (nc & 1) ? wu : wg;
    const float* ssrc = (nc & 1) ? su : sg;
    float sc = ssrc[(f >> 7) * 40 + (k >> 7)];
    size_t si = (size_t)f * 5120 + k;
    f32x4 a = *(const f32x4*)(wsrc + si);
    f32x4 b = *(const f32x4*)(wsrc + si + 4);
    bf16x8 o;
#pragma unroll
    for (int i = 0; i < 4; ++i) {
      o[i] = (__bf16)(a[i] * sc);
      o[i + 4] = (__bf16)(b[i] * sc);
    }
    *(bf16x8*)(wq + (size_t)g * 8) = o;
  } else {
    // wdq fragment-major (NT=48, 20 col-blocks of 256; nc = H row).
    unsigned g = (unsigned)(bid - 28160) * 256u + (unsigned)tid;
    unsigned lane = g & 63u, c = lane & 15u, q = lane >> 4;
    unsigned fr = (g >> 6) & 15u;
    unsigned u = g >> 10;            // bx*48 + t  (< 960)
    unsigned bx = u / 48u;
    unsigned t = u - bx * 48u;
    unsigned nc = (bx << 8) | (fr << 4) | c;
    unsigned k = (t << 5) | (q << 3);
    float sc = sd[(nc >> 7) * 12 + (k >> 7)];
    size_t si = (size_t)nc * 1536 + k;
    f32x4 a = *(const f32x4*)(wd + si);
    f32x4 b = *(const f32x4*)(wd + si + 4);
    bf16x8 o;
#pragma unroll
    for (int i = 0; i < 4; ++i) {
      o[i] = (__bf16)(a[i] * sc);
      o[i + 4] = (__bf16)(b[i] * sc);
    }
    *(bf16x8*)(wdq + (size_t)g * 8) = o;
  }
}

// ---- flatmm GEMM: C = A @ Bfm^T -------------------------------------------
// A:[M,K] bf16 row-major. Bfm: fragment-major weights (see prep).
// Tile 128(M) x 256(N), 4 waves; A ring-4 LDS; B in regs.
template <bool FUSE_SILU, typename OutT>
__global__ __launch_bounds__(256, 2) void gemm_p(
    const __bf16* __restrict__ A, const __bf16* __restrict__ Bfm,
    OutT* __restrict__ C, int M, int N, int K, int ldc, int nbx) {
  __shared__ __bf16 lds[4 * 4096];  // 4 ring slots x A 8 KB
  const int tid = threadIdx.x;
  const int lane = tid & 63;
  const int wave = tid >> 6;
  const int lr = lane & 15;
  const int NT = K >> 5, NTm1 = NT - 1;

  // bijective XCD-chunked swizzle (gridDim.x % 8 == 0)
  const int nwg = gridDim.x;
  const int lb = (blockIdx.x & 7) * (nwg >> 3) + (blockIdx.x >> 3);
  const int bx = lb % nbx;
  const int by = lb / nbx;
  const int m0 = by * 128, n0 = bx * 256;

  // A-fragment byte offset within 1KB subtile (R4-verified swizzle pair)
  int laneoff = (lr << 6) | ((lane >> 4) << 4);
  laneoff ^= ((lr & 2) << 3) | ((lr & 8) << 2);

  // A staging: 2 chunks/thread, inverse-swizzled source, linear dest
  int r0, k0, r1, k1;
  chunk_rk(tid, r0, k0);
  chunk_rk(tid + 256, r1, k1);
  const unsigned o0 = (unsigned)r0 * K + (unsigned)k0;
  const unsigned o1 = (unsigned)r1 * K + (unsigned)k1;
  const int d0 = tid << 3, d1 = (tid + 256) << 3;
  const __bf16* Ab = A + (size_t)m0 * K;
  // B fragment base for this wave: frags wave*4 + j, chunk-lane = lane.
  const __bf16* Bf =
      Bfm + ((size_t)bx * NT * 16 + wave * 4) * 512 + (size_t)lane * 8;

  f32x4 acc[8][4] = {};
  bf16x8 af[4];
  u32x4 bgA[4], bgB[4];

  auto STAGE_A = [&](int t_, int s_) {
    __bf16* lp = lds + s_ * 4096;
    const unsigned ko = (unsigned)t_ << 5;
    glds16(Ab + (o0 + ko), lp + d0);
    glds16(Ab + (o1 + ko), lp + d1);
  };
  auto RD_A = [&](const char* cb, int h) {
#pragma unroll
    for (int i = 0; i < 4; ++i)
      af[i] = *(const bf16x8*)(cb + (((h << 2) + i) << 10) + laneoff);
  };
  auto MFMA16 = [&](int h, u32x4 (&bk)[4]) {
    __builtin_amdgcn_s_setprio(1);
#pragma unroll
    for (int j = 0; j < 4; ++j) {
      bf16x8 b = __builtin_bit_cast(bf16x8, bk[j]);
#pragma unroll
      for (int i = 0; i < 4; ++i)
        acc[(h << 2) + i][j] = __builtin_amdgcn_mfma_f32_16x16x32_bf16(
            af[i], b, acc[(h << 2) + i][j], 0, 0, 0);
    }
    __builtin_amdgcn_s_setprio(0);
  };

#define B_LOAD(t_, B_)                                                       \
  {                                                                          \
    const __bf16* bp = Bf + (size_t)(t_) * 8192;                             \
    asm volatile("global_load_dwordx4 %0, %1, off" : "=v"(B_[0]) : "v"(bp)); \
    asm volatile("global_load_dwordx4 %0, %1, off offset:1024"               \
                 : "=v"(B_[1]) : "v"(bp));                                   \
    asm volatile("global_load_dwordx4 %0, %1, off offset:2048"               \
                 : "=v"(B_[2]) : "v"(bp));                                   \
    asm volatile("global_load_dwordx4 %0, %1, off offset:3072"               \
                 : "=v"(B_[3]) : "v"(bp));                                   \
  }

  // prologue: A0,B0,A1,B1 in that vm order (12 outstanding)
  STAGE_A(0, 0);
  B_LOAD(0, bgA);
  STAGE_A(1, 1);
  B_LOAD(1, bgB);

  // per kslice: VMBAR(6) drains A(t)+B(t), leaves t+1's 6 in flight;
  // then issue A(t+2)+B(t+2) (B after MFMAs: WAR-safe reg reuse).
#define KSTEP(u_, B_)                                \
  {                                                  \
    int tn = t + (u_) + 2;                           \
    if (tn > NTm1) tn = NTm1; /* uniform tail */     \
    const char* cb = (const char*)lds + (u_) * 8192; \
    VMBAR(6);                                        \
    RD_A(cb, 0);                                     \
    STAGE_A(tn, ((u_) + 2) & 3);                     \
    LGKM0();                                         \
    MFMA16(0, B_);                                   \
    RD_A(cb, 1);                                     \
    LGKM0();                                         \
    MFMA16(1, B_);                                   \
    B_LOAD(tn, B_);                                  \
  }

  for (int t = 0; t < NT; t += 4) {  // NT % 4 == 0 (160 / 48)
    KSTEP(0, bgA);
    KSTEP(1, bgB);
    KSTEP(2, bgA);
    KSTEP(3, bgB);
  }
  VMBAR(0);  // drain redundant tail loads before epilogue/exit
#undef KSTEP
#undef B_LOAD

  // C/D layout (m89-verified): col = lane&15, row = (lane>>4)*4 + reg.
  const int colb = n0 + (wave << 6) + lr;
  const int rowb = m0 + ((lane >> 4) << 2);
#pragma unroll
  for (int i = 0; i < 8; ++i)
#pragma unroll
    for (int j = 0; j < 4; ++j)
#pragma unroll
      for (int r = 0; r < 4; ++r) {
        if constexpr (FUSE_SILU) {
          // lanes (2k,2k+1) hold cols (gate_f, up_f) of the same row.
          float v = acc[i][j][r];
          float p = __shfl_xor(v, 1, 64);
          float g = (lane & 1) ? p : v;
          float u = (lane & 1) ? v : p;
          float hv = (g / (1.0f + __expf(-g))) * u;
          if ((lane & 1) == 0)
            C[(size_t)(rowb + i * 16 + r) * ldc + ((colb + j * 16) >> 1)] =
                (OutT)hv;
        } else {
          C[(size_t)(rowb + i * 16 + r) * ldc + (colb + j * 16)] =
              (OutT)acc[i][j][r];
        }
      }
}

extern "C" void kernel_launch(void* const* d_in, const int* in_sizes, int n_in,
                              void* d_out, int out_size, void* d_ws,
                              size_t ws_size, hipStream_t stream) {
  const int Hd = 5120, Fd = 1536, Td = 8192;
  const float* x = (const float*)d_in[0];
  const float* wg = (const float*)d_in[1];
  const float* sg = (const float*)d_in[2];
  const float* wu = (const float*)d_in[3];
  const float* su = (const float*)d_in[4];
  const float* wd = (const float*)d_in[5];
  const float* sd = (const float*)d_in[6];
  float* out = (float*)d_out;

  // ws layout (bf16): xb [T*H] | wqf [2F*H] | wdqf [H*F] | h [T*F]  ~156 MB
  __bf16* ws = (__bf16*)d_ws;
  const size_t xsz = (size_t)Td * Hd;
  __bf16* xb = ws;
  __bf16* wqf = xb + xsz;
  __bf16* wdqf = wqf + (size_t)2 * Fd * Hd;
  __bf16* hbuf = wdqf + (size_t)Hd * Fd;

  prep<<<32000, 256, 0, stream>>>(x, wg, sg, wu, su, wd, sd, xb, wqf, wdqf);

  // gemm1: [8192 x 3072] = xb @ wq^T, silu-pair epilogue -> h [8192][1536]
  // grid = (8192/128) * (3072/256) = 64 * 12 = 768 (%8==0); 2 blk/CU
  gemm_p<true, __bf16><<<768, 256, 0, stream>>>(xb, wqf, hbuf, Td, 2 * Fd, Hd,
                                                Fd, 12);

  // gemm2: [8192 x 5120] = h @ wdq^T -> out f32
  // grid = 64 * 20 = 1280 (%8==0); 2 blk/CU
  gemm_p<false, float><<<1280, 256, 0, stream>>>(hbuf, wdqf, out, Td, Hd, Fd,
                                                 Hd, 20);
}